// Round 18
// baseline (488.818 us; speedup 1.0000x reference)
//
#include <hip/hip_runtime.h>
#include <stdint.h>

typedef unsigned short u16;
typedef float f32x4 __attribute__((ext_vector_type(4)));
typedef short short8 __attribute__((ext_vector_type(8)));  // 8 bf16 in 4 VGPRs

__device__ __forceinline__ u16 f2bf(float f) {
  union { float f; uint32_t u; } v; v.f = f;
  return (u16)((v.u + 0x7FFFu + ((v.u >> 16) & 1u)) >> 16);
}
__device__ __forceinline__ uint32_t pack2(u16 lo, u16 hi) {
  return (uint32_t)lo | ((uint32_t)hi << 16);
}
// Async global->LDS DMA, 16B/lane: LDS dest = wave-uniform base + lane*16,
// global src = per-lane address. Zero VGPR staging.
__device__ __forceinline__ void gld_lds16(const void* gsrc, void* ldst) {
  __builtin_amdgcn_global_load_lds(
      (const __attribute__((address_space(1))) unsigned int*)gsrc,
      (__attribute__((address_space(3))) unsigned int*)ldst, 16, 0, 0);
}

#define MFMA16(a, b, c) __builtin_amdgcn_mfma_f32_16x16x32_bf16((a), (b), (c), 0, 0, 0)

// ---------------------------------------------------------------------------
// Weight fp32 -> bf16 conversion (Wv, Wo)
// ---------------------------------------------------------------------------
__global__ void conv_w(const float* __restrict__ src, u16* __restrict__ dst, int n4) {
  int i = blockIdx.x * blockDim.x + threadIdx.x;
  if (i >= n4) return;
  float4 v = ((const float4*)src)[i];
  uint2 p;
  p.x = pack2(f2bf(v.x), f2bf(v.y));
  p.y = pack2(f2bf(v.z), f2bf(v.w));
  ((uint2*)dst)[i] = p;
}

// Wq (pre-scaled by log2e) + Wk -> Wqkb[64][512] bf16 (rows 0-31 Q, 32-63 K)
__global__ void conv_wqk(const float* __restrict__ Wq, const float* __restrict__ Wk,
                         u16* __restrict__ dst) {
  int i = blockIdx.x * blockDim.x + threadIdx.x;  // float4 index, 8192 total
  if (i >= 8192) return;
  const float LOG2E = 1.4426950408889634f;
  bool isQ = i < 4096;
  float4 v = isQ ? ((const float4*)Wq)[i] : ((const float4*)Wk)[i - 4096];
  float s = isQ ? LOG2E : 1.0f;
  uint2 p;
  p.x = pack2(f2bf(v.x * s), f2bf(v.y * s));
  p.y = pack2(f2bf(v.z * s), f2bf(v.w * s));
  ((uint2*)dst)[i] = p;
}

// ---------------------------------------------------------------------------
// Fused QKV projection (single x read) + x prefetch ping-pong (round 17,
// verified). V2 swizzled-tile layout; Q (log2e-scaled) / K via MFMA.
// ---------------------------------------------------------------------------
__global__ __launch_bounds__(256) void qkv_proj(
    const float* __restrict__ x, const u16* __restrict__ Wvb,
    const u16* __restrict__ Wqkb, const float* __restrict__ bv,
    const float* __restrict__ bq, const float* __restrict__ bk,
    u16* __restrict__ V2, u16* __restrict__ Qb, u16* __restrict__ Kb) {
  const int b = blockIdx.y, nb = blockIdx.x * 64;
  const int t = threadIdx.x, w = t >> 6, lane = t & 63, g = lane >> 4, l15 = lane & 15;
  const int wo = (w >> 1) * 32, wn = (w & 1) * 32;
  __shared__ __align__(16) u16 xT[64][64];  // row = n (128B rows), swizzled

  f32x4 zero4 = {0.f, 0.f, 0.f, 0.f};
  f32x4 acc[8][2][2];
#pragma unroll
  for (int og = 0; og < 8; ++og)
#pragma unroll
    for (int ot = 0; ot < 2; ++ot)
#pragma unroll
      for (int nt = 0; nt < 2; ++nt) acc[og][ot][nt] = zero4;
  f32x4 accq[2][2];
  accq[0][0] = zero4; accq[0][1] = zero4; accq[1][0] = zero4; accq[1][1] = zero4;

  const int cq4 = (t >> 4) * 4, n4 = (t & 15) * 4;
  const size_t xrow = (size_t)(b * 512) * 4096 + nb + n4;

  float4 cur0 = *(const float4*)&x[xrow + (size_t)(cq4 + 0) * 4096];
  float4 cur1 = *(const float4*)&x[xrow + (size_t)(cq4 + 1) * 4096];
  float4 cur2 = *(const float4*)&x[xrow + (size_t)(cq4 + 2) * 4096];
  float4 cur3 = *(const float4*)&x[xrow + (size_t)(cq4 + 3) * 4096];

#pragma unroll
  for (int ci = 0; ci < 8; ++ci) {
    const int c0 = ci * 64;
    float4 nxt0, nxt1, nxt2, nxt3;
    if (ci < 7) {
      nxt0 = *(const float4*)&x[xrow + (size_t)(c0 + 64 + cq4 + 0) * 4096];
      nxt1 = *(const float4*)&x[xrow + (size_t)(c0 + 64 + cq4 + 1) * 4096];
      nxt2 = *(const float4*)&x[xrow + (size_t)(c0 + 64 + cq4 + 2) * 4096];
      nxt3 = *(const float4*)&x[xrow + (size_t)(c0 + 64 + cq4 + 3) * 4096];
    }
    float rr[4][4];
    rr[0][0] = cur0.x; rr[0][1] = cur0.y; rr[0][2] = cur0.z; rr[0][3] = cur0.w;
    rr[1][0] = cur1.x; rr[1][1] = cur1.y; rr[1][2] = cur1.z; rr[1][3] = cur1.w;
    rr[2][0] = cur2.x; rr[2][1] = cur2.y; rr[2][2] = cur2.z; rr[2][3] = cur2.w;
    rr[3][0] = cur3.x; rr[3][1] = cur3.y; rr[3][2] = cur3.z; rr[3][3] = cur3.w;
#pragma unroll
    for (int k = 0; k < 4; ++k) {
      int row = n4 + k;
      uint2 pk;
      pk.x = pack2(f2bf(rr[0][k]), f2bf(rr[1][k]));
      pk.y = pack2(f2bf(rr[2][k]), f2bf(rr[3][k]));
      int byte = row * 128 + ((cq4 * 2) ^ ((row & 7) << 4));
      *(uint2*)((char*)&xT[0][0] + byte) = pk;
    }
    __syncthreads();

    short8 bb[2][2];
#pragma unroll
    for (int nt = 0; nt < 2; ++nt)
#pragma unroll
      for (int ks = 0; ks < 2; ++ks) {
        int row = wn + nt * 16 + l15;
        int byte = row * 128 + (((ks * 64) + (g * 16)) ^ ((row & 7) << 4));
        bb[nt][ks] = *(const short8*)((const char*)&xT[0][0] + byte);
      }
#pragma unroll
    for (int og = 0; og < 8; ++og) {
      short8 af[2][2];
#pragma unroll
      for (int ot = 0; ot < 2; ++ot)
#pragma unroll
        for (int ks = 0; ks < 2; ++ks)
          af[ot][ks] = *(const short8*)&Wvb[(size_t)(og * 64 + wo + ot * 16 + l15) * 512 + c0 + ks * 32 + g * 8];
#pragma unroll
      for (int ks = 0; ks < 2; ++ks)
#pragma unroll
        for (int ot = 0; ot < 2; ++ot)
#pragma unroll
          for (int nt = 0; nt < 2; ++nt)
            acc[og][ot][nt] = MFMA16(af[ot][ks], bb[nt][ks], acc[og][ot][nt]);
    }
    {
      short8 aq[2][2];
#pragma unroll
      for (int ot = 0; ot < 2; ++ot)
#pragma unroll
        for (int ks = 0; ks < 2; ++ks)
          aq[ot][ks] = *(const short8*)&Wqkb[(size_t)(wo + ot * 16 + l15) * 512 + c0 + ks * 32 + g * 8];
#pragma unroll
      for (int ks = 0; ks < 2; ++ks)
#pragma unroll
        for (int ot = 0; ot < 2; ++ot)
#pragma unroll
          for (int nt = 0; nt < 2; ++nt)
            accq[ot][nt] = MFMA16(aq[ot][ks], bb[nt][ks], accq[ot][nt]);
    }
    __syncthreads();
    if (ci < 7) { cur0 = nxt0; cur1 = nxt1; cur2 = nxt2; cur3 = nxt3; }
  }

  const size_t tbase = (size_t)b * 2097152 + (size_t)(nb >> 6) * 32768;
#pragma unroll
  for (int og = 0; og < 8; ++og)
#pragma unroll
    for (int ot = 0; ot < 2; ++ot)
#pragma unroll
      for (int nt = 0; nt < 2; ++nt)
#pragma unroll
        for (int r = 0; r < 4; ++r) {
          int o = og * 64 + wo + ot * 16 + g * 4 + r;
          int kk = wn + nt * 16 + l15;
          int swz = ((kk * 2) ^ ((o & 7) << 4)) >> 1;
          V2[tbase + o * 64 + swz] = f2bf(acc[og][ot][nt][r] + bv[o]);
        }
  const float LOG2E = 1.4426950408889634f;
#pragma unroll
  for (int ot = 0; ot < 2; ++ot)
#pragma unroll
    for (int nt = 0; nt < 2; ++nt)
#pragma unroll
      for (int r = 0; r < 4; ++r) {
        int o = wo + ot * 16 + g * 4 + r;   // 0..63: Q rows then K rows
        int n = nb + wn + nt * 16 + l15;
        if (o < 32) {
          Qb[((size_t)(b * 4096 + n)) * 32 + o] = f2bf(accq[ot][nt][r] + bq[o] * LOG2E);
        } else {
          Kb[((size_t)(b * 4096 + n)) * 32 + (o - 32)] = f2bf(accq[ot][nt][r] + bk[o - 32]);
        }
      }
}

// ---------------------------------------------------------------------------
// Fused flash attention + Wo + residual, 1024-THREAD blocks (16 waves,
// 4 waves/SIMD): per-thread acc halves to 64 f32 -> forced <=128 unified
// regs/wave via launch_bounds(1024,4). Algorithm = round-16 (asymmetric
// S-waves, pf-preread pipeline): waves (qg=w&3 32q, chh=w>>2 128ch);
// chh0 waves (one per SIMD, 3 PV-only partners each) compute S+softmax in
// 4 sequential 16-key slices (register-lean). Same V2/Plds/AO mappings.
// ---------------------------------------------------------------------------
__global__ __launch_bounds__(1024, 4) void attn_f(
    const u16* __restrict__ Qb, const u16* __restrict__ Kb,
    const u16* __restrict__ V2, const u16* __restrict__ Wob,
    const float* __restrict__ bo, const float* __restrict__ gamma,
    const float* __restrict__ x, float* __restrict__ out) {
  const int bid = blockIdx.x;
  const int b = bid & 7;                 // XCD-pinned batch
  const int qblk = (bid >> 3) * 128;
  const int t = threadIdx.x;
  const int w = t >> 6, lane = t & 63, g = lane >> 4, l15 = lane & 15;
  const int qg = w & 3, chh = w >> 2;    // SIMD w&3 hosts S-wave qg + 3 PV waves
  const int qbase = qblk + qg * 32;
  const int chb = chh * 128;

  __shared__ __align__(16) u16 Vlds[2][32768];   // [buf][512ch][64k]; reused as AO
  __shared__ __align__(16) u16 Plds[4][32][88];  // per q-group, shared
  __shared__ float lsum[4][32];

  f32x4 zero4 = {0.f, 0.f, 0.f, 0.f};

  short8 qf[2];
  if (chh == 0) {
#pragma unroll
    for (int qt = 0; qt < 2; ++qt)
      qf[qt] = *(const short8*)&Qb[((size_t)(b * 4096 + qbase + qt * 16 + l15)) * 32 + g * 8];
  }

  f32x4 acc[2][8];   // 32q x 128ch
#pragma unroll
  for (int qt = 0; qt < 2; ++qt)
#pragma unroll
    for (int ct = 0; ct < 8; ++ct) acc[qt][ct] = zero4;
  float l_[2][4] = {{0.f, 0.f, 0.f, 0.f}, {0.f, 0.f, 0.f, 0.f}};

  const char* VBb = (const char*)(V2 + (size_t)b * 2097152);  // byte base
  const size_t kb0 = (size_t)b * 4096;

  // ---- prologue: DMA V(0) (wave w: 4KB slice); chh0 builds P(0) ----
  {
    const char* gsrc = VBb + w * 4096 + lane * 16;
    char* ldst = (char*)&Vlds[0][0] + w * 4096;
#pragma unroll
    for (int j = 0; j < 4; ++j) gld_lds16(gsrc + j * 1024, ldst + j * 1024);
  }
  if (chh == 0) {
#pragma unroll
    for (int sl = 0; sl < 4; ++sl) {
      short8 kf = *(const short8*)&Kb[(kb0 + 0 + sl * 16 + l15) * 32 + g * 8];
      f32x4 s0 = MFMA16(qf[0], kf, zero4);
      f32x4 s1 = MFMA16(qf[1], kf, zero4);
#pragma unroll
      for (int qt = 0; qt < 2; ++qt)
#pragma unroll
        for (int r = 0; r < 4; ++r) {
          float p = exp2f(qt ? s1[r] : s0[r]);
          Plds[qg][qt * 16 + g * 4 + r][sl * 16 + l15] = f2bf(p);
          float rs = p;
          rs += __shfl_xor(rs, 1);
          rs += __shfl_xor(rs, 2);
          rs += __shfl_xor(rs, 4);
          rs += __shfl_xor(rs, 8);
          l_[qt][r] += rs;
        }
    }
  }
  asm volatile("s_waitcnt vmcnt(0) lgkmcnt(0)" ::: "memory");
  __builtin_amdgcn_s_barrier();
  __builtin_amdgcn_sched_barrier(0);

  for (int kv = 0; kv < 4096; kv += 64) {
    const int buf = (kv >> 6) & 1;
    const bool more = (kv + 64) < 4096;

    // 1) DMA V(t+1) -> buf^1
    if (more) {
      const char* gsrc = VBb + (size_t)((kv >> 6) + 1) * 65536 + w * 4096 + lane * 16;
      char* ldst = (char*)&Vlds[buf ^ 1][0] + w * 4096;
#pragma unroll
      for (int j = 0; j < 4; ++j) gld_lds16(gsrc + j * 1024, ldst + j * 1024);
    }

    // 2) pre-read pf(t) — after this Plds is dead
    short8 pf[2][2];
#pragma unroll
    for (int qt = 0; qt < 2; ++qt)
#pragma unroll
      for (int k2 = 0; k2 < 2; ++k2)
        pf[qt][k2] = *(const short8*)&Plds[qg][qt * 16 + l15][k2 * 32 + g * 8];

    // mid-barrier: pf consumed by all waves; Plds free for P(t+1)
    asm volatile("s_waitcnt lgkmcnt(0)" ::: "memory");
    __builtin_amdgcn_s_barrier();
    __builtin_amdgcn_sched_barrier(0);

    // 3) chh0: S+softmax(t+1), 4 sequential 16-key slices (register-lean);
    //    overlaps the 3 PV-only waves per SIMD via TLP.
    if (chh == 0 && more) {
#pragma unroll
      for (int sl = 0; sl < 4; ++sl) {
        short8 kf = *(const short8*)&Kb[(kb0 + kv + 64 + sl * 16 + l15) * 32 + g * 8];
        f32x4 s0 = MFMA16(qf[0], kf, zero4);
        f32x4 s1 = MFMA16(qf[1], kf, zero4);
#pragma unroll
        for (int qt = 0; qt < 2; ++qt)
#pragma unroll
          for (int r = 0; r < 4; ++r) {
            float p = exp2f(qt ? s1[r] : s0[r]);
            Plds[qg][qt * 16 + g * 4 + r][sl * 16 + l15] = f2bf(p);
            float rs = p;
            rs += __shfl_xor(rs, 1);
            rs += __shfl_xor(rs, 2);
            rs += __shfl_xor(rs, 4);
            rs += __shfl_xor(rs, 8);
            l_[qt][r] += rs;
          }
      }
    }

    // 4) PV(t): 32q x 128ch; V from Vlds[buf], P from pre-read pf
#pragma unroll
    for (int ct = 0; ct < 8; ++ct) {
      int c = chb + ct * 16 + l15;
      int sw = (c & 7) << 4;
      const char* vrow = (const char*)&Vlds[buf][0] + c * 128;
      short8 vf0 = *(const short8*)(vrow + ((g * 16) ^ sw));
      short8 vf1 = *(const short8*)(vrow + ((64 + g * 16) ^ sw));
      acc[0][ct] = MFMA16(pf[0][0], vf0, acc[0][ct]);
      acc[0][ct] = MFMA16(pf[0][1], vf1, acc[0][ct]);
      acc[1][ct] = MFMA16(pf[1][0], vf0, acc[1][ct]);
      acc[1][ct] = MFMA16(pf[1][1], vf1, acc[1][ct]);
    }

    // end barrier: P(t+1) visible, PV(t) reads done, DMA(t+1) retired
    asm volatile("s_waitcnt vmcnt(0) lgkmcnt(0)" ::: "memory");
    __builtin_amdgcn_s_barrier();
    __builtin_amdgcn_sched_barrier(0);
  }

  // ---- epilogue part 1: share row sums ----
  if (chh == 0 && l15 == 0) {
#pragma unroll
    for (int qt = 0; qt < 2; ++qt)
#pragma unroll
      for (int r = 0; r < 4; ++r)
        lsum[qg][qt * 16 + g * 4 + r] = l_[qt][r];
  }
  __syncthreads();

  // ---- epilogue part 2: normalize AO into LDS (reuse Vlds) ----
  // AO layout: [n 0..127][c 0..511] u16, 1KB rows, elem col ^= ((n&7)<<3).
  u16* AO = (u16*)&Vlds[0][0];
#pragma unroll
  for (int qt = 0; qt < 2; ++qt) {
    float inv[4];
#pragma unroll
    for (int r = 0; r < 4; ++r) inv[r] = 1.0f / lsum[qg][qt * 16 + g * 4 + r];
#pragma unroll
    for (int ct = 0; ct < 8; ++ct)
#pragma unroll
      for (int r = 0; r < 4; ++r) {
        int nrow = qg * 32 + qt * 16 + g * 4 + r;   // block-local q row
        int c = chb + ct * 16 + l15;
        AO[nrow * 512 + (c ^ ((nrow & 7) << 3))] = f2bf(acc[qt][ct][r] * inv[r]);
      }
  }
  __syncthreads();

  // ---- epilogue part 3: out = gamma*(Wo @ AO + bo) + x ----
  // wave w: o rows w*32 .. w*32+31; n = qblk .. qblk+127.
  f32x4 oacc[2][8];
#pragma unroll
  for (int ot = 0; ot < 2; ++ot)
#pragma unroll
    for (int nt = 0; nt < 8; ++nt) oacc[ot][nt] = zero4;

  for (int c0 = 0; c0 < 512; c0 += 64) {
#pragma unroll
    for (int nth = 0; nth < 2; ++nth) {     // nt halves to bound reg pressure
      short8 bb[4][2];
#pragma unroll
      for (int n2 = 0; n2 < 4; ++n2)
#pragma unroll
        for (int ks = 0; ks < 2; ++ks) {
          int row = (nth * 4 + n2) * 16 + l15;
          int coff = (c0 + ks * 32 + g * 8) ^ ((row & 7) << 3);
          bb[n2][ks] = *(const short8*)&AO[row * 512 + coff];
        }
#pragma unroll
      for (int ot = 0; ot < 2; ++ot) {
        short8 af[2];
#pragma unroll
        for (int ks = 0; ks < 2; ++ks)
          af[ks] = *(const short8*)&Wob[(size_t)(w * 32 + ot * 16 + l15) * 512 + c0 + ks * 32 + g * 8];
#pragma unroll
        for (int ks = 0; ks < 2; ++ks)
#pragma unroll
          for (int n2 = 0; n2 < 4; ++n2)
            oacc[ot][nth * 4 + n2] = MFMA16(af[ks], bb[n2][ks], oacc[ot][nth * 4 + n2]);
      }
    }
  }

  float gm = gamma[0];
#pragma unroll
  for (int ot = 0; ot < 2; ++ot)
#pragma unroll
    for (int nt = 0; nt < 8; ++nt)
#pragma unroll
      for (int r = 0; r < 4; ++r) {
        int o = w * 32 + ot * 16 + g * 4 + r;
        int n = qblk + nt * 16 + l15;
        size_t idx = ((size_t)(b * 512 + o)) * 4096 + n;
        out[idx] = gm * (oacc[ot][nt][r] + bo[o]) + x[idx];
      }
}

// ---------------------------------------------------------------------------
// Workspace map (38.9 MB):
//   V2 ws+0 (32MB, swizzled-tile V) | Qb ws+32M (2MB) | Kb ws+34M (2MB)
//   Wvb +36M (0.5MB) | Wob (0.5MB) | Wqkb (64KB)
//   d_out holds ONLY the final fp32 output (attn_f writes it directly).
// ---------------------------------------------------------------------------
extern "C" void kernel_launch(void* const* d_in, const int* in_sizes, int n_in,
                              void* d_out, int out_size, void* d_ws, size_t ws_size,
                              hipStream_t stream) {
  (void)in_sizes; (void)n_in; (void)out_size; (void)ws_size;
  const float* x     = (const float*)d_in[0];
  const float* Wq    = (const float*)d_in[1];
  const float* bq    = (const float*)d_in[2];
  const float* Wk    = (const float*)d_in[3];
  const float* bk    = (const float*)d_in[4];
  const float* Wv    = (const float*)d_in[5];
  const float* bv    = (const float*)d_in[6];
  const float* Wo    = (const float*)d_in[7];
  const float* bo    = (const float*)d_in[8];
  const float* gamma = (const float*)d_in[9];

  char* wsb = (char*)d_ws;
  u16* V2   = (u16*)(wsb + 0);
  u16* Qb   = (u16*)(wsb + (size_t)33554432);
  u16* Kb   = (u16*)(wsb + (size_t)35651584);
  u16* Wvb  = (u16*)(wsb + (size_t)37748736);
  u16* Wob  = (u16*)(wsb + (size_t)38273024);
  u16* Wqkb = (u16*)(wsb + (size_t)38797312);

  conv_w<<<256, 256, 0, stream>>>(Wv, Wvb, 65536);
  conv_w<<<256, 256, 0, stream>>>(Wo, Wob, 65536);
  conv_wqk<<<32, 256, 0, stream>>>(Wq, Wk, Wqkb);
  qkv_proj<<<dim3(64, 8), 256, 0, stream>>>(x, Wvb, Wqkb, bv, bq, bk, V2, Qb, Kb);
  attn_f<<<256, 1024, 0, stream>>>(Qb, Kb, V2, Wob, bo, gamma, x, (float*)d_out);
}

// Round 19
// 333.568 us; speedup vs baseline: 1.4654x; 1.4654x over previous
//
#include <hip/hip_runtime.h>
#include <stdint.h>

typedef unsigned short u16;
typedef float f32x4 __attribute__((ext_vector_type(4)));
typedef short short8 __attribute__((ext_vector_type(8)));  // 8 bf16 in 4 VGPRs

__device__ __forceinline__ u16 f2bf(float f) {
  union { float f; uint32_t u; } v; v.f = f;
  return (u16)((v.u + 0x7FFFu + ((v.u >> 16) & 1u)) >> 16);
}
__device__ __forceinline__ uint32_t pack2(u16 lo, u16 hi) {
  return (uint32_t)lo | ((uint32_t)hi << 16);
}
// Async global->LDS DMA, 16B/lane: LDS dest = wave-uniform base + lane*16,
// global src = per-lane address. Zero VGPR staging.
__device__ __forceinline__ void gld_lds16(const void* gsrc, void* ldst) {
  __builtin_amdgcn_global_load_lds(
      (const __attribute__((address_space(1))) unsigned int*)gsrc,
      (__attribute__((address_space(3))) unsigned int*)ldst, 16, 0, 0);
}

#define MFMA16(a, b, c) __builtin_amdgcn_mfma_f32_16x16x32_bf16((a), (b), (c), 0, 0, 0)

// ---------------------------------------------------------------------------
// Weight fp32 -> bf16 conversion (Wv, Wo)
// ---------------------------------------------------------------------------
__global__ void conv_w(const float* __restrict__ src, u16* __restrict__ dst, int n4) {
  int i = blockIdx.x * blockDim.x + threadIdx.x;
  if (i >= n4) return;
  float4 v = ((const float4*)src)[i];
  uint2 p;
  p.x = pack2(f2bf(v.x), f2bf(v.y));
  p.y = pack2(f2bf(v.z), f2bf(v.w));
  ((uint2*)dst)[i] = p;
}

// Wq (pre-scaled by log2e) + Wk -> Wqkb[64][512] bf16 (rows 0-31 Q, 32-63 K)
__global__ void conv_wqk(const float* __restrict__ Wq, const float* __restrict__ Wk,
                         u16* __restrict__ dst) {
  int i = blockIdx.x * blockDim.x + threadIdx.x;  // float4 index, 8192 total
  if (i >= 8192) return;
  const float LOG2E = 1.4426950408889634f;
  bool isQ = i < 4096;
  float4 v = isQ ? ((const float4*)Wq)[i] : ((const float4*)Wk)[i - 4096];
  float s = isQ ? LOG2E : 1.0f;
  uint2 p;
  p.x = pack2(f2bf(v.x * s), f2bf(v.y * s));
  p.y = pack2(f2bf(v.z * s), f2bf(v.w * s));
  ((uint2*)dst)[i] = p;
}

// ---------------------------------------------------------------------------
// Fused QKV projection (single x read) + x prefetch ping-pong (round 17,
// verified). V2 swizzled-tile layout; Q (log2e-scaled) / K via MFMA.
// ---------------------------------------------------------------------------
__global__ __launch_bounds__(256) void qkv_proj(
    const float* __restrict__ x, const u16* __restrict__ Wvb,
    const u16* __restrict__ Wqkb, const float* __restrict__ bv,
    const float* __restrict__ bq, const float* __restrict__ bk,
    u16* __restrict__ V2, u16* __restrict__ Qb, u16* __restrict__ Kb) {
  const int b = blockIdx.y, nb = blockIdx.x * 64;
  const int t = threadIdx.x, w = t >> 6, lane = t & 63, g = lane >> 4, l15 = lane & 15;
  const int wo = (w >> 1) * 32, wn = (w & 1) * 32;
  __shared__ __align__(16) u16 xT[64][64];  // row = n (128B rows), swizzled

  f32x4 zero4 = {0.f, 0.f, 0.f, 0.f};
  f32x4 acc[8][2][2];
#pragma unroll
  for (int og = 0; og < 8; ++og)
#pragma unroll
    for (int ot = 0; ot < 2; ++ot)
#pragma unroll
      for (int nt = 0; nt < 2; ++nt) acc[og][ot][nt] = zero4;
  f32x4 accq[2][2];
  accq[0][0] = zero4; accq[0][1] = zero4; accq[1][0] = zero4; accq[1][1] = zero4;

  const int cq4 = (t >> 4) * 4, n4 = (t & 15) * 4;
  const size_t xrow = (size_t)(b * 512) * 4096 + nb + n4;

  float4 cur0 = *(const float4*)&x[xrow + (size_t)(cq4 + 0) * 4096];
  float4 cur1 = *(const float4*)&x[xrow + (size_t)(cq4 + 1) * 4096];
  float4 cur2 = *(const float4*)&x[xrow + (size_t)(cq4 + 2) * 4096];
  float4 cur3 = *(const float4*)&x[xrow + (size_t)(cq4 + 3) * 4096];

#pragma unroll
  for (int ci = 0; ci < 8; ++ci) {
    const int c0 = ci * 64;
    float4 nxt0, nxt1, nxt2, nxt3;
    if (ci < 7) {
      nxt0 = *(const float4*)&x[xrow + (size_t)(c0 + 64 + cq4 + 0) * 4096];
      nxt1 = *(const float4*)&x[xrow + (size_t)(c0 + 64 + cq4 + 1) * 4096];
      nxt2 = *(const float4*)&x[xrow + (size_t)(c0 + 64 + cq4 + 2) * 4096];
      nxt3 = *(const float4*)&x[xrow + (size_t)(c0 + 64 + cq4 + 3) * 4096];
    }
    float rr[4][4];
    rr[0][0] = cur0.x; rr[0][1] = cur0.y; rr[0][2] = cur0.z; rr[0][3] = cur0.w;
    rr[1][0] = cur1.x; rr[1][1] = cur1.y; rr[1][2] = cur1.z; rr[1][3] = cur1.w;
    rr[2][0] = cur2.x; rr[2][1] = cur2.y; rr[2][2] = cur2.z; rr[2][3] = cur2.w;
    rr[3][0] = cur3.x; rr[3][1] = cur3.y; rr[3][2] = cur3.z; rr[3][3] = cur3.w;
#pragma unroll
    for (int k = 0; k < 4; ++k) {
      int row = n4 + k;
      uint2 pk;
      pk.x = pack2(f2bf(rr[0][k]), f2bf(rr[1][k]));
      pk.y = pack2(f2bf(rr[2][k]), f2bf(rr[3][k]));
      int byte = row * 128 + ((cq4 * 2) ^ ((row & 7) << 4));
      *(uint2*)((char*)&xT[0][0] + byte) = pk;
    }
    __syncthreads();

    short8 bb[2][2];
#pragma unroll
    for (int nt = 0; nt < 2; ++nt)
#pragma unroll
      for (int ks = 0; ks < 2; ++ks) {
        int row = wn + nt * 16 + l15;
        int byte = row * 128 + (((ks * 64) + (g * 16)) ^ ((row & 7) << 4));
        bb[nt][ks] = *(const short8*)((const char*)&xT[0][0] + byte);
      }
#pragma unroll
    for (int og = 0; og < 8; ++og) {
      short8 af[2][2];
#pragma unroll
      for (int ot = 0; ot < 2; ++ot)
#pragma unroll
        for (int ks = 0; ks < 2; ++ks)
          af[ot][ks] = *(const short8*)&Wvb[(size_t)(og * 64 + wo + ot * 16 + l15) * 512 + c0 + ks * 32 + g * 8];
#pragma unroll
      for (int ks = 0; ks < 2; ++ks)
#pragma unroll
        for (int ot = 0; ot < 2; ++ot)
#pragma unroll
          for (int nt = 0; nt < 2; ++nt)
            acc[og][ot][nt] = MFMA16(af[ot][ks], bb[nt][ks], acc[og][ot][nt]);
    }
    {
      short8 aq[2][2];
#pragma unroll
      for (int ot = 0; ot < 2; ++ot)
#pragma unroll
        for (int ks = 0; ks < 2; ++ks)
          aq[ot][ks] = *(const short8*)&Wqkb[(size_t)(wo + ot * 16 + l15) * 512 + c0 + ks * 32 + g * 8];
#pragma unroll
      for (int ks = 0; ks < 2; ++ks)
#pragma unroll
        for (int ot = 0; ot < 2; ++ot)
#pragma unroll
          for (int nt = 0; nt < 2; ++nt)
            accq[ot][nt] = MFMA16(aq[ot][ks], bb[nt][ks], accq[ot][nt]);
    }
    __syncthreads();
    if (ci < 7) { cur0 = nxt0; cur1 = nxt1; cur2 = nxt2; cur3 = nxt3; }
  }

  const size_t tbase = (size_t)b * 2097152 + (size_t)(nb >> 6) * 32768;
#pragma unroll
  for (int og = 0; og < 8; ++og)
#pragma unroll
    for (int ot = 0; ot < 2; ++ot)
#pragma unroll
      for (int nt = 0; nt < 2; ++nt)
#pragma unroll
        for (int r = 0; r < 4; ++r) {
          int o = og * 64 + wo + ot * 16 + g * 4 + r;
          int kk = wn + nt * 16 + l15;
          int swz = ((kk * 2) ^ ((o & 7) << 4)) >> 1;
          V2[tbase + o * 64 + swz] = f2bf(acc[og][ot][nt][r] + bv[o]);
        }
  const float LOG2E = 1.4426950408889634f;
#pragma unroll
  for (int ot = 0; ot < 2; ++ot)
#pragma unroll
    for (int nt = 0; nt < 2; ++nt)
#pragma unroll
      for (int r = 0; r < 4; ++r) {
        int o = wo + ot * 16 + g * 4 + r;   // 0..63: Q rows then K rows
        int n = nb + wn + nt * 16 + l15;
        if (o < 32) {
          Qb[((size_t)(b * 4096 + n)) * 32 + o] = f2bf(accq[ot][nt][r] + bq[o] * LOG2E);
        } else {
          Kb[((size_t)(b * 4096 + n)) * 32 + (o - 32)] = f2bf(accq[ot][nt][r] + bk[o - 32]);
        }
      }
}

// ---------------------------------------------------------------------------
// Fused flash attention + Wo projection + residual, SOFTMAX-PIPELINED
// (round-16 structure, verified 251us — best of the family; r17/r18
// variants both regressed). 8 waves (qg=w&3 32q, chh=w>>2 256ch);
// chh0 waves: S+softmax; pf(t) pre-read -> mid-barrier -> S+P(t+1)
// overlapping PV(t) via TLP -> end barrier.
// ---------------------------------------------------------------------------
__global__ __launch_bounds__(512, 1) void attn_f(
    const u16* __restrict__ Qb, const u16* __restrict__ Kb,
    const u16* __restrict__ V2, const u16* __restrict__ Wob,
    const float* __restrict__ bo, const float* __restrict__ gamma,
    const float* __restrict__ x, float* __restrict__ out) {
  const int bid = blockIdx.x;
  const int b = bid & 7;                 // XCD-pinned batch
  const int qblk = (bid >> 3) * 128;
  const int t = threadIdx.x;
  const int w = t >> 6, lane = t & 63, g = lane >> 4, l15 = lane & 15;
  const int qg = w & 3, chh = w >> 2;    // SIMD i hosts (qg=i,chh=0)+(qg=i,chh=1)
  const int qbase = qblk + qg * 32;
  const int chb = chh * 256;

  __shared__ __align__(16) u16 Vlds[2][32768];   // [buf][512ch][64k]; reused as AO
  __shared__ __align__(16) u16 Plds[4][32][88];  // per q-group, shared
  __shared__ float lsum[4][32];

  f32x4 zero4 = {0.f, 0.f, 0.f, 0.f};

  short8 qf[2];
  if (chh == 0) {
#pragma unroll
    for (int qt = 0; qt < 2; ++qt)
      qf[qt] = *(const short8*)&Qb[((size_t)(b * 4096 + qbase + qt * 16 + l15)) * 32 + g * 8];
  }

  f32x4 acc[2][16];
#pragma unroll
  for (int qt = 0; qt < 2; ++qt)
#pragma unroll
    for (int ct = 0; ct < 16; ++ct) acc[qt][ct] = zero4;
  float l_[2][4] = {{0.f, 0.f, 0.f, 0.f}, {0.f, 0.f, 0.f, 0.f}};

  const char* VBb = (const char*)(V2 + (size_t)b * 2097152);  // byte base
  const size_t kb0 = (size_t)b * 4096;

  // ---- prologue: DMA V(0); chh0 builds P(0) ----
  {
    const char* gsrc = VBb + w * 8192 + lane * 16;
    char* ldst = (char*)&Vlds[0][0] + w * 8192;
#pragma unroll
    for (int j = 0; j < 8; ++j) gld_lds16(gsrc + j * 1024, ldst + j * 1024);
  }
  if (chh == 0) {
    float rsv[2][4];
#pragma unroll
    for (int half = 0; half < 2; ++half) {
      short8 kfA = *(const short8*)&Kb[(kb0 + 0 + half * 32 + 0 + l15) * 32 + g * 8];
      short8 kfB = *(const short8*)&Kb[(kb0 + 0 + half * 32 + 16 + l15) * 32 + g * 8];
      f32x4 sA[2], sB[2];
      sA[0] = MFMA16(qf[0], kfA, zero4); sA[1] = MFMA16(qf[1], kfA, zero4);
      sB[0] = MFMA16(qf[0], kfB, zero4); sB[1] = MFMA16(qf[1], kfB, zero4);
#pragma unroll
      for (int qt = 0; qt < 2; ++qt)
#pragma unroll
        for (int r = 0; r < 4; ++r) {
          float pA = exp2f(sA[qt][r]), pB = exp2f(sB[qt][r]);
          Plds[qg][qt * 16 + g * 4 + r][(half * 2 + 0) * 16 + l15] = f2bf(pA);
          Plds[qg][qt * 16 + g * 4 + r][(half * 2 + 1) * 16 + l15] = f2bf(pB);
          float v = pA + pB;
          rsv[qt][r] = half ? (rsv[qt][r] + v) : v;
        }
    }
#pragma unroll
    for (int qt = 0; qt < 2; ++qt)
#pragma unroll
      for (int r = 0; r < 4; ++r) {
        float rs = rsv[qt][r];
        rs += __shfl_xor(rs, 1);
        rs += __shfl_xor(rs, 2);
        rs += __shfl_xor(rs, 4);
        rs += __shfl_xor(rs, 8);
        l_[qt][r] += rs;
      }
  }
  asm volatile("s_waitcnt vmcnt(0) lgkmcnt(0)" ::: "memory");
  __builtin_amdgcn_s_barrier();
  __builtin_amdgcn_sched_barrier(0);

  for (int kv = 0; kv < 4096; kv += 64) {
    const int buf = (kv >> 6) & 1;
    const bool more = (kv + 64) < 4096;

    // 1) DMA V(t+1) -> buf^1 (its old content V(t-1) freed by end barrier)
    if (more) {
      const char* gsrc = VBb + (size_t)((kv >> 6) + 1) * 65536 + w * 8192 + lane * 16;
      char* ldst = (char*)&Vlds[buf ^ 1][0] + w * 8192;
#pragma unroll
      for (int j = 0; j < 8; ++j) gld_lds16(gsrc + j * 1024, ldst + j * 1024);
    }

    // 2) pre-read pf(t) — after this Plds is dead
    short8 pf[2][2];
#pragma unroll
    for (int qt = 0; qt < 2; ++qt)
#pragma unroll
      for (int k2 = 0; k2 < 2; ++k2)
        pf[qt][k2] = *(const short8*)&Plds[qg][qt * 16 + l15][k2 * 32 + g * 8];

    // mid-barrier: pf consumed by all waves; Plds free for P(t+1)
    asm volatile("s_waitcnt lgkmcnt(0)" ::: "memory");
    __builtin_amdgcn_s_barrier();
    __builtin_amdgcn_sched_barrier(0);

    // 3) chh0: S+softmax(t+1) into Plds (overlaps PV(t) via chh1's TLP)
    if (chh == 0 && more) {
      float rsv[2][4];
#pragma unroll
      for (int half = 0; half < 2; ++half) {
        short8 kfA = *(const short8*)&Kb[(kb0 + kv + 64 + half * 32 + 0 + l15) * 32 + g * 8];
        short8 kfB = *(const short8*)&Kb[(kb0 + kv + 64 + half * 32 + 16 + l15) * 32 + g * 8];
        f32x4 sA[2], sB[2];
        sA[0] = MFMA16(qf[0], kfA, zero4); sA[1] = MFMA16(qf[1], kfA, zero4);
        sB[0] = MFMA16(qf[0], kfB, zero4); sB[1] = MFMA16(qf[1], kfB, zero4);
#pragma unroll
        for (int qt = 0; qt < 2; ++qt)
#pragma unroll
          for (int r = 0; r < 4; ++r) {
            float pA = exp2f(sA[qt][r]), pB = exp2f(sB[qt][r]);
            Plds[qg][qt * 16 + g * 4 + r][(half * 2 + 0) * 16 + l15] = f2bf(pA);
            Plds[qg][qt * 16 + g * 4 + r][(half * 2 + 1) * 16 + l15] = f2bf(pB);
            float v = pA + pB;
            rsv[qt][r] = half ? (rsv[qt][r] + v) : v;
          }
      }
#pragma unroll
      for (int qt = 0; qt < 2; ++qt)
#pragma unroll
        for (int r = 0; r < 4; ++r) {
          float rs = rsv[qt][r];
          rs += __shfl_xor(rs, 1);
          rs += __shfl_xor(rs, 2);
          rs += __shfl_xor(rs, 4);
          rs += __shfl_xor(rs, 8);
          l_[qt][r] += rs;
        }
    }

    // 4) PV(t): both ch-halves, V from Vlds[buf], P from pre-read pf
#pragma unroll
    for (int ct = 0; ct < 16; ++ct) {
      int c = chb + ct * 16 + l15;
      int sw = (c & 7) << 4;
      const char* vrow = (const char*)&Vlds[buf][0] + c * 128;
      short8 vf0 = *(const short8*)(vrow + ((g * 16) ^ sw));
      short8 vf1 = *(const short8*)(vrow + ((64 + g * 16) ^ sw));
      acc[0][ct] = MFMA16(pf[0][0], vf0, acc[0][ct]);
      acc[0][ct] = MFMA16(pf[0][1], vf1, acc[0][ct]);
      acc[1][ct] = MFMA16(pf[1][0], vf0, acc[1][ct]);
      acc[1][ct] = MFMA16(pf[1][1], vf1, acc[1][ct]);
    }

    // end barrier: P(t+1) visible, PV(t) LDS reads done, DMA(t+1) retired
    asm volatile("s_waitcnt vmcnt(0) lgkmcnt(0)" ::: "memory");
    __builtin_amdgcn_s_barrier();
    __builtin_amdgcn_sched_barrier(0);
  }

  // ---- epilogue part 1: share row sums ----
  if (chh == 0 && l15 == 0) {
#pragma unroll
    for (int qt = 0; qt < 2; ++qt)
#pragma unroll
      for (int r = 0; r < 4; ++r)
        lsum[qg][qt * 16 + g * 4 + r] = l_[qt][r];
  }
  __syncthreads();

  // ---- epilogue part 2: normalize AO into LDS (reuse Vlds) ----
  // AO layout: [n 0..127][c 0..511] u16, 1KB rows, elem col ^= ((n&7)<<3).
  u16* AO = (u16*)&Vlds[0][0];
#pragma unroll
  for (int qt = 0; qt < 2; ++qt) {
    float inv[4];
#pragma unroll
    for (int r = 0; r < 4; ++r) inv[r] = 1.0f / lsum[qg][qt * 16 + g * 4 + r];
#pragma unroll
    for (int ct = 0; ct < 16; ++ct)
#pragma unroll
      for (int r = 0; r < 4; ++r) {
        int nrow = qg * 32 + qt * 16 + g * 4 + r;   // block-local q row
        int c = chb + ct * 16 + l15;
        AO[nrow * 512 + (c ^ ((nrow & 7) << 3))] = f2bf(acc[qt][ct][r] * inv[r]);
      }
  }
  __syncthreads();

  // ---- epilogue part 3: out = gamma*(Wo @ AO + bo) + x ----
  // wave w: o rows w*64 .. w*64+63; n = qblk .. qblk+127.
  f32x4 oacc[4][8];
#pragma unroll
  for (int ot = 0; ot < 4; ++ot)
#pragma unroll
    for (int nt = 0; nt < 8; ++nt) oacc[ot][nt] = zero4;

  for (int c0 = 0; c0 < 512; c0 += 64) {
#pragma unroll
    for (int nth = 0; nth < 2; ++nth) {     // nt halves to bound reg pressure
      short8 bb[4][2];
#pragma unroll
      for (int n2 = 0; n2 < 4; ++n2)
#pragma unroll
        for (int ks = 0; ks < 2; ++ks) {
          int row = (nth * 4 + n2) * 16 + l15;
          int coff = (c0 + ks * 32 + g * 8) ^ ((row & 7) << 3);
          bb[n2][ks] = *(const short8*)&AO[row * 512 + coff];
        }
#pragma unroll
      for (int ot = 0; ot < 4; ++ot) {
        short8 af[2];
#pragma unroll
        for (int ks = 0; ks < 2; ++ks)
          af[ks] = *(const short8*)&Wob[(size_t)(w * 64 + ot * 16 + l15) * 512 + c0 + ks * 32 + g * 8];
#pragma unroll
        for (int ks = 0; ks < 2; ++ks)
#pragma unroll
          for (int n2 = 0; n2 < 4; ++n2)
            oacc[ot][nth * 4 + n2] = MFMA16(af[ks], bb[n2][ks], oacc[ot][nth * 4 + n2]);
      }
    }
  }

  float gm = gamma[0];
#pragma unroll
  for (int ot = 0; ot < 4; ++ot)
#pragma unroll
    for (int nt = 0; nt < 8; ++nt)
#pragma unroll
      for (int r = 0; r < 4; ++r) {
        int o = w * 64 + ot * 16 + g * 4 + r;
        int n = qblk + nt * 16 + l15;
        size_t idx = ((size_t)(b * 512 + o)) * 4096 + n;
        out[idx] = gm * (oacc[ot][nt][r] + bo[o]) + x[idx];
      }
}

// ---------------------------------------------------------------------------
// Workspace map (38.9 MB):
//   V2 ws+0 (32MB, swizzled-tile V) | Qb ws+32M (2MB) | Kb ws+34M (2MB)
//   Wvb +36M (0.5MB) | Wob (0.5MB) | Wqkb (64KB)
//   d_out holds ONLY the final fp32 output (attn_f writes it directly).
// ---------------------------------------------------------------------------
extern "C" void kernel_launch(void* const* d_in, const int* in_sizes, int n_in,
                              void* d_out, int out_size, void* d_ws, size_t ws_size,
                              hipStream_t stream) {
  (void)in_sizes; (void)n_in; (void)out_size; (void)ws_size;
  const float* x     = (const float*)d_in[0];
  const float* Wq    = (const float*)d_in[1];
  const float* bq    = (const float*)d_in[2];
  const float* Wk    = (const float*)d_in[3];
  const float* bk    = (const float*)d_in[4];
  const float* Wv    = (const float*)d_in[5];
  const float* bv    = (const float*)d_in[6];
  const float* Wo    = (const float*)d_in[7];
  const float* bo    = (const float*)d_in[8];
  const float* gamma = (const float*)d_in[9];

  char* wsb = (char*)d_ws;
  u16* V2   = (u16*)(wsb + 0);
  u16* Qb   = (u16*)(wsb + (size_t)33554432);
  u16* Kb   = (u16*)(wsb + (size_t)35651584);
  u16* Wvb  = (u16*)(wsb + (size_t)37748736);
  u16* Wob  = (u16*)(wsb + (size_t)38273024);
  u16* Wqkb = (u16*)(wsb + (size_t)38797312);

  conv_w<<<256, 256, 0, stream>>>(Wv, Wvb, 65536);
  conv_w<<<256, 256, 0, stream>>>(Wo, Wob, 65536);
  conv_wqk<<<32, 256, 0, stream>>>(Wq, Wk, Wqkb);
  qkv_proj<<<dim3(64, 8), 256, 0, stream>>>(x, Wvb, Wqkb, bv, bq, bk, V2, Qb, Kb);
  attn_f<<<256, 512, 0, stream>>>(Qb, Kb, V2, Wob, bo, gamma, x, (float*)d_out);
}

// Round 20
// 329.516 us; speedup vs baseline: 1.4834x; 1.0123x over previous
//
#include <hip/hip_runtime.h>
#include <stdint.h>

typedef unsigned short u16;
typedef float f32x4 __attribute__((ext_vector_type(4)));
typedef short short8 __attribute__((ext_vector_type(8)));  // 8 bf16 in 4 VGPRs

__device__ __forceinline__ u16 f2bf(float f) {
  union { float f; uint32_t u; } v; v.f = f;
  return (u16)((v.u + 0x7FFFu + ((v.u >> 16) & 1u)) >> 16);
}
__device__ __forceinline__ uint32_t pack2(u16 lo, u16 hi) {
  return (uint32_t)lo | ((uint32_t)hi << 16);
}
// Async global->LDS DMA, 16B/lane: LDS dest = wave-uniform base + lane*16,
// global src = per-lane address. Zero VGPR staging.
__device__ __forceinline__ void gld_lds16(const void* gsrc, void* ldst) {
  __builtin_amdgcn_global_load_lds(
      (const __attribute__((address_space(1))) unsigned int*)gsrc,
      (__attribute__((address_space(3))) unsigned int*)ldst, 16, 0, 0);
}

#define MFMA16(a, b, c) __builtin_amdgcn_mfma_f32_16x16x32_bf16((a), (b), (c), 0, 0, 0)

// ---------------------------------------------------------------------------
// Weight fp32 -> bf16 conversion (Wv, Wo)
// ---------------------------------------------------------------------------
__global__ void conv_w(const float* __restrict__ src, u16* __restrict__ dst, int n4) {
  int i = blockIdx.x * blockDim.x + threadIdx.x;
  if (i >= n4) return;
  float4 v = ((const float4*)src)[i];
  uint2 p;
  p.x = pack2(f2bf(v.x), f2bf(v.y));
  p.y = pack2(f2bf(v.z), f2bf(v.w));
  ((uint2*)dst)[i] = p;
}

// Wq (pre-scaled by log2e) + Wk -> Wqkb[64][512] bf16 (rows 0-31 Q, 32-63 K)
__global__ void conv_wqk(const float* __restrict__ Wq, const float* __restrict__ Wk,
                         u16* __restrict__ dst) {
  int i = blockIdx.x * blockDim.x + threadIdx.x;  // float4 index, 8192 total
  if (i >= 8192) return;
  const float LOG2E = 1.4426950408889634f;
  bool isQ = i < 4096;
  float4 v = isQ ? ((const float4*)Wq)[i] : ((const float4*)Wk)[i - 4096];
  float s = isQ ? LOG2E : 1.0f;
  uint2 p;
  p.x = pack2(f2bf(v.x * s), f2bf(v.y * s));
  p.y = pack2(f2bf(v.z * s), f2bf(v.w * s));
  ((uint2*)dst)[i] = p;
}

// ---------------------------------------------------------------------------
// Fused QKV projection, OG-SPLIT (grid z in {0,1}: 4 og-groups each; z=0
// also computes Q/K). Halves per-thread acc (128->64 regs) -> ~3 waves/SIMD
// (r19: monolithic og-loop held ~210 VGPRs at 2 waves/SIMD, latency-bound).
// x read twice; same-(nb,b) block pairs share x tiles via L2.
// x prefetch ping-pong kept (r17, verified).
// ---------------------------------------------------------------------------
__global__ __launch_bounds__(256) void qkv_proj(
    const float* __restrict__ x, const u16* __restrict__ Wvb,
    const u16* __restrict__ Wqkb, const float* __restrict__ bv,
    const float* __restrict__ bq, const float* __restrict__ bk,
    u16* __restrict__ V2, u16* __restrict__ Qb, u16* __restrict__ Kb) {
  const int b = blockIdx.y, nb = blockIdx.x * 64;
  const int oh = blockIdx.z;               // og half: 0 -> og 0..3 (+QK), 1 -> og 4..7
  const int t = threadIdx.x, w = t >> 6, lane = t & 63, g = lane >> 4, l15 = lane & 15;
  const int wo = (w >> 1) * 32, wn = (w & 1) * 32;
  __shared__ __align__(16) u16 xT[64][64];  // row = n (128B rows), swizzled

  f32x4 zero4 = {0.f, 0.f, 0.f, 0.f};
  f32x4 acc[4][2][2];
#pragma unroll
  for (int og = 0; og < 4; ++og)
#pragma unroll
    for (int ot = 0; ot < 2; ++ot)
#pragma unroll
      for (int nt = 0; nt < 2; ++nt) acc[og][ot][nt] = zero4;
  f32x4 accq[2][2];
  accq[0][0] = zero4; accq[0][1] = zero4; accq[1][0] = zero4; accq[1][1] = zero4;

  const int cq4 = (t >> 4) * 4, n4 = (t & 15) * 4;
  const size_t xrow = (size_t)(b * 512) * 4096 + nb + n4;

  float4 cur0 = *(const float4*)&x[xrow + (size_t)(cq4 + 0) * 4096];
  float4 cur1 = *(const float4*)&x[xrow + (size_t)(cq4 + 1) * 4096];
  float4 cur2 = *(const float4*)&x[xrow + (size_t)(cq4 + 2) * 4096];
  float4 cur3 = *(const float4*)&x[xrow + (size_t)(cq4 + 3) * 4096];

#pragma unroll
  for (int ci = 0; ci < 8; ++ci) {
    const int c0 = ci * 64;
    float4 nxt0, nxt1, nxt2, nxt3;
    if (ci < 7) {
      nxt0 = *(const float4*)&x[xrow + (size_t)(c0 + 64 + cq4 + 0) * 4096];
      nxt1 = *(const float4*)&x[xrow + (size_t)(c0 + 64 + cq4 + 1) * 4096];
      nxt2 = *(const float4*)&x[xrow + (size_t)(c0 + 64 + cq4 + 2) * 4096];
      nxt3 = *(const float4*)&x[xrow + (size_t)(c0 + 64 + cq4 + 3) * 4096];
    }
    float rr[4][4];
    rr[0][0] = cur0.x; rr[0][1] = cur0.y; rr[0][2] = cur0.z; rr[0][3] = cur0.w;
    rr[1][0] = cur1.x; rr[1][1] = cur1.y; rr[1][2] = cur1.z; rr[1][3] = cur1.w;
    rr[2][0] = cur2.x; rr[2][1] = cur2.y; rr[2][2] = cur2.z; rr[2][3] = cur2.w;
    rr[3][0] = cur3.x; rr[3][1] = cur3.y; rr[3][2] = cur3.z; rr[3][3] = cur3.w;
#pragma unroll
    for (int k = 0; k < 4; ++k) {
      int row = n4 + k;
      uint2 pk;
      pk.x = pack2(f2bf(rr[0][k]), f2bf(rr[1][k]));
      pk.y = pack2(f2bf(rr[2][k]), f2bf(rr[3][k]));
      int byte = row * 128 + ((cq4 * 2) ^ ((row & 7) << 4));
      *(uint2*)((char*)&xT[0][0] + byte) = pk;
    }
    __syncthreads();

    short8 bb[2][2];
#pragma unroll
    for (int nt = 0; nt < 2; ++nt)
#pragma unroll
      for (int ks = 0; ks < 2; ++ks) {
        int row = wn + nt * 16 + l15;
        int byte = row * 128 + (((ks * 64) + (g * 16)) ^ ((row & 7) << 4));
        bb[nt][ks] = *(const short8*)((const char*)&xT[0][0] + byte);
      }
#pragma unroll
    for (int og = 0; og < 4; ++og) {
      short8 af[2][2];
#pragma unroll
      for (int ot = 0; ot < 2; ++ot)
#pragma unroll
        for (int ks = 0; ks < 2; ++ks)
          af[ot][ks] = *(const short8*)&Wvb[(size_t)((oh * 4 + og) * 64 + wo + ot * 16 + l15) * 512 + c0 + ks * 32 + g * 8];
#pragma unroll
      for (int ks = 0; ks < 2; ++ks)
#pragma unroll
        for (int ot = 0; ot < 2; ++ot)
#pragma unroll
          for (int nt = 0; nt < 2; ++nt)
            acc[og][ot][nt] = MFMA16(af[ot][ks], bb[nt][ks], acc[og][ot][nt]);
    }
    if (oh == 0) {
      short8 aq[2][2];
#pragma unroll
      for (int ot = 0; ot < 2; ++ot)
#pragma unroll
        for (int ks = 0; ks < 2; ++ks)
          aq[ot][ks] = *(const short8*)&Wqkb[(size_t)(wo + ot * 16 + l15) * 512 + c0 + ks * 32 + g * 8];
#pragma unroll
      for (int ks = 0; ks < 2; ++ks)
#pragma unroll
        for (int ot = 0; ot < 2; ++ot)
#pragma unroll
          for (int nt = 0; nt < 2; ++nt)
            accq[ot][nt] = MFMA16(aq[ot][ks], bb[nt][ks], accq[ot][nt]);
    }
    __syncthreads();
    if (ci < 7) { cur0 = nxt0; cur1 = nxt1; cur2 = nxt2; cur3 = nxt3; }
  }

  const size_t tbase = (size_t)b * 2097152 + (size_t)(nb >> 6) * 32768;
#pragma unroll
  for (int og = 0; og < 4; ++og)
#pragma unroll
    for (int ot = 0; ot < 2; ++ot)
#pragma unroll
      for (int nt = 0; nt < 2; ++nt)
#pragma unroll
        for (int r = 0; r < 4; ++r) {
          int o = (oh * 4 + og) * 64 + wo + ot * 16 + g * 4 + r;
          int kk = wn + nt * 16 + l15;
          int swz = ((kk * 2) ^ ((o & 7) << 4)) >> 1;
          V2[tbase + o * 64 + swz] = f2bf(acc[og][ot][nt][r] + bv[o]);
        }
  if (oh == 0) {
    const float LOG2E = 1.4426950408889634f;
#pragma unroll
    for (int ot = 0; ot < 2; ++ot)
#pragma unroll
      for (int nt = 0; nt < 2; ++nt)
#pragma unroll
        for (int r = 0; r < 4; ++r) {
          int o = wo + ot * 16 + g * 4 + r;   // 0..63: Q rows then K rows
          int n = nb + wn + nt * 16 + l15;
          if (o < 32) {
            Qb[((size_t)(b * 4096 + n)) * 32 + o] = f2bf(accq[ot][nt][r] + bq[o] * LOG2E);
          } else {
            Kb[((size_t)(b * 4096 + n)) * 32 + (o - 32)] = f2bf(accq[ot][nt][r] + bk[o - 32]);
          }
        }
  }
}

// ---------------------------------------------------------------------------
// Fused flash attention + Wo projection + residual, SOFTMAX-PIPELINED
// (round-16 structure, verified 251us — best of the family; r17/r18
// variants both regressed). 8 waves (qg=w&3 32q, chh=w>>2 256ch);
// chh0 waves: S+softmax; pf(t) pre-read -> mid-barrier -> S+P(t+1)
// overlapping PV(t) via TLP -> end barrier. UNCHANGED from round 19.
// ---------------------------------------------------------------------------
__global__ __launch_bounds__(512, 1) void attn_f(
    const u16* __restrict__ Qb, const u16* __restrict__ Kb,
    const u16* __restrict__ V2, const u16* __restrict__ Wob,
    const float* __restrict__ bo, const float* __restrict__ gamma,
    const float* __restrict__ x, float* __restrict__ out) {
  const int bid = blockIdx.x;
  const int b = bid & 7;                 // XCD-pinned batch
  const int qblk = (bid >> 3) * 128;
  const int t = threadIdx.x;
  const int w = t >> 6, lane = t & 63, g = lane >> 4, l15 = lane & 15;
  const int qg = w & 3, chh = w >> 2;    // SIMD i hosts (qg=i,chh=0)+(qg=i,chh=1)
  const int qbase = qblk + qg * 32;
  const int chb = chh * 256;

  __shared__ __align__(16) u16 Vlds[2][32768];   // [buf][512ch][64k]; reused as AO
  __shared__ __align__(16) u16 Plds[4][32][88];  // per q-group, shared
  __shared__ float lsum[4][32];

  f32x4 zero4 = {0.f, 0.f, 0.f, 0.f};

  short8 qf[2];
  if (chh == 0) {
#pragma unroll
    for (int qt = 0; qt < 2; ++qt)
      qf[qt] = *(const short8*)&Qb[((size_t)(b * 4096 + qbase + qt * 16 + l15)) * 32 + g * 8];
  }

  f32x4 acc[2][16];
#pragma unroll
  for (int qt = 0; qt < 2; ++qt)
#pragma unroll
    for (int ct = 0; ct < 16; ++ct) acc[qt][ct] = zero4;
  float l_[2][4] = {{0.f, 0.f, 0.f, 0.f}, {0.f, 0.f, 0.f, 0.f}};

  const char* VBb = (const char*)(V2 + (size_t)b * 2097152);  // byte base
  const size_t kb0 = (size_t)b * 4096;

  // ---- prologue: DMA V(0); chh0 builds P(0) ----
  {
    const char* gsrc = VBb + w * 8192 + lane * 16;
    char* ldst = (char*)&Vlds[0][0] + w * 8192;
#pragma unroll
    for (int j = 0; j < 8; ++j) gld_lds16(gsrc + j * 1024, ldst + j * 1024);
  }
  if (chh == 0) {
    float rsv[2][4];
#pragma unroll
    for (int half = 0; half < 2; ++half) {
      short8 kfA = *(const short8*)&Kb[(kb0 + 0 + half * 32 + 0 + l15) * 32 + g * 8];
      short8 kfB = *(const short8*)&Kb[(kb0 + 0 + half * 32 + 16 + l15) * 32 + g * 8];
      f32x4 sA[2], sB[2];
      sA[0] = MFMA16(qf[0], kfA, zero4); sA[1] = MFMA16(qf[1], kfA, zero4);
      sB[0] = MFMA16(qf[0], kfB, zero4); sB[1] = MFMA16(qf[1], kfB, zero4);
#pragma unroll
      for (int qt = 0; qt < 2; ++qt)
#pragma unroll
        for (int r = 0; r < 4; ++r) {
          float pA = exp2f(sA[qt][r]), pB = exp2f(sB[qt][r]);
          Plds[qg][qt * 16 + g * 4 + r][(half * 2 + 0) * 16 + l15] = f2bf(pA);
          Plds[qg][qt * 16 + g * 4 + r][(half * 2 + 1) * 16 + l15] = f2bf(pB);
          float v = pA + pB;
          rsv[qt][r] = half ? (rsv[qt][r] + v) : v;
        }
    }
#pragma unroll
    for (int qt = 0; qt < 2; ++qt)
#pragma unroll
      for (int r = 0; r < 4; ++r) {
        float rs = rsv[qt][r];
        rs += __shfl_xor(rs, 1);
        rs += __shfl_xor(rs, 2);
        rs += __shfl_xor(rs, 4);
        rs += __shfl_xor(rs, 8);
        l_[qt][r] += rs;
      }
  }
  asm volatile("s_waitcnt vmcnt(0) lgkmcnt(0)" ::: "memory");
  __builtin_amdgcn_s_barrier();
  __builtin_amdgcn_sched_barrier(0);

  for (int kv = 0; kv < 4096; kv += 64) {
    const int buf = (kv >> 6) & 1;
    const bool more = (kv + 64) < 4096;

    // 1) DMA V(t+1) -> buf^1 (its old content V(t-1) freed by end barrier)
    if (more) {
      const char* gsrc = VBb + (size_t)((kv >> 6) + 1) * 65536 + w * 8192 + lane * 16;
      char* ldst = (char*)&Vlds[buf ^ 1][0] + w * 8192;
#pragma unroll
      for (int j = 0; j < 8; ++j) gld_lds16(gsrc + j * 1024, ldst + j * 1024);
    }

    // 2) pre-read pf(t) — after this Plds is dead
    short8 pf[2][2];
#pragma unroll
    for (int qt = 0; qt < 2; ++qt)
#pragma unroll
      for (int k2 = 0; k2 < 2; ++k2)
        pf[qt][k2] = *(const short8*)&Plds[qg][qt * 16 + l15][k2 * 32 + g * 8];

    // mid-barrier: pf consumed by all waves; Plds free for P(t+1)
    asm volatile("s_waitcnt lgkmcnt(0)" ::: "memory");
    __builtin_amdgcn_s_barrier();
    __builtin_amdgcn_sched_barrier(0);

    // 3) chh0: S+softmax(t+1) into Plds (overlaps PV(t) via chh1's TLP)
    if (chh == 0 && more) {
      float rsv[2][4];
#pragma unroll
      for (int half = 0; half < 2; ++half) {
        short8 kfA = *(const short8*)&Kb[(kb0 + kv + 64 + half * 32 + 0 + l15) * 32 + g * 8];
        short8 kfB = *(const short8*)&Kb[(kb0 + kv + 64 + half * 32 + 16 + l15) * 32 + g * 8];
        f32x4 sA[2], sB[2];
        sA[0] = MFMA16(qf[0], kfA, zero4); sA[1] = MFMA16(qf[1], kfA, zero4);
        sB[0] = MFMA16(qf[0], kfB, zero4); sB[1] = MFMA16(qf[1], kfB, zero4);
#pragma unroll
        for (int qt = 0; qt < 2; ++qt)
#pragma unroll
          for (int r = 0; r < 4; ++r) {
            float pA = exp2f(sA[qt][r]), pB = exp2f(sB[qt][r]);
            Plds[qg][qt * 16 + g * 4 + r][(half * 2 + 0) * 16 + l15] = f2bf(pA);
            Plds[qg][qt * 16 + g * 4 + r][(half * 2 + 1) * 16 + l15] = f2bf(pB);
            float v = pA + pB;
            rsv[qt][r] = half ? (rsv[qt][r] + v) : v;
          }
      }
#pragma unroll
      for (int qt = 0; qt < 2; ++qt)
#pragma unroll
        for (int r = 0; r < 4; ++r) {
          float rs = rsv[qt][r];
          rs += __shfl_xor(rs, 1);
          rs += __shfl_xor(rs, 2);
          rs += __shfl_xor(rs, 4);
          rs += __shfl_xor(rs, 8);
          l_[qt][r] += rs;
        }
    }

    // 4) PV(t): both ch-halves, V from Vlds[buf], P from pre-read pf
#pragma unroll
    for (int ct = 0; ct < 16; ++ct) {
      int c = chb + ct * 16 + l15;
      int sw = (c & 7) << 4;
      const char* vrow = (const char*)&Vlds[buf][0] + c * 128;
      short8 vf0 = *(const short8*)(vrow + ((g * 16) ^ sw));
      short8 vf1 = *(const short8*)(vrow + ((64 + g * 16) ^ sw));
      acc[0][ct] = MFMA16(pf[0][0], vf0, acc[0][ct]);
      acc[0][ct] = MFMA16(pf[0][1], vf1, acc[0][ct]);
      acc[1][ct] = MFMA16(pf[1][0], vf0, acc[1][ct]);
      acc[1][ct] = MFMA16(pf[1][1], vf1, acc[1][ct]);
    }

    // end barrier: P(t+1) visible, PV(t) LDS reads done, DMA(t+1) retired
    asm volatile("s_waitcnt vmcnt(0) lgkmcnt(0)" ::: "memory");
    __builtin_amdgcn_s_barrier();
    __builtin_amdgcn_sched_barrier(0);
  }

  // ---- epilogue part 1: share row sums ----
  if (chh == 0 && l15 == 0) {
#pragma unroll
    for (int qt = 0; qt < 2; ++qt)
#pragma unroll
      for (int r = 0; r < 4; ++r)
        lsum[qg][qt * 16 + g * 4 + r] = l_[qt][r];
  }
  __syncthreads();

  // ---- epilogue part 2: normalize AO into LDS (reuse Vlds) ----
  // AO layout: [n 0..127][c 0..511] u16, 1KB rows, elem col ^= ((n&7)<<3).
  u16* AO = (u16*)&Vlds[0][0];
#pragma unroll
  for (int qt = 0; qt < 2; ++qt) {
    float inv[4];
#pragma unroll
    for (int r = 0; r < 4; ++r) inv[r] = 1.0f / lsum[qg][qt * 16 + g * 4 + r];
#pragma unroll
    for (int ct = 0; ct < 16; ++ct)
#pragma unroll
      for (int r = 0; r < 4; ++r) {
        int nrow = qg * 32 + qt * 16 + g * 4 + r;   // block-local q row
        int c = chb + ct * 16 + l15;
        AO[nrow * 512 + (c ^ ((nrow & 7) << 3))] = f2bf(acc[qt][ct][r] * inv[r]);
      }
  }
  __syncthreads();

  // ---- epilogue part 3: out = gamma*(Wo @ AO + bo) + x ----
  // wave w: o rows w*64 .. w*64+63; n = qblk .. qblk+127.
  f32x4 oacc[4][8];
#pragma unroll
  for (int ot = 0; ot < 4; ++ot)
#pragma unroll
    for (int nt = 0; nt < 8; ++nt) oacc[ot][nt] = zero4;

  for (int c0 = 0; c0 < 512; c0 += 64) {
#pragma unroll
    for (int nth = 0; nth < 2; ++nth) {     // nt halves to bound reg pressure
      short8 bb[4][2];
#pragma unroll
      for (int n2 = 0; n2 < 4; ++n2)
#pragma unroll
        for (int ks = 0; ks < 2; ++ks) {
          int row = (nth * 4 + n2) * 16 + l15;
          int coff = (c0 + ks * 32 + g * 8) ^ ((row & 7) << 3);
          bb[n2][ks] = *(const short8*)&AO[row * 512 + coff];
        }
#pragma unroll
      for (int ot = 0; ot < 4; ++ot) {
        short8 af[2];
#pragma unroll
        for (int ks = 0; ks < 2; ++ks)
          af[ks] = *(const short8*)&Wob[(size_t)(w * 64 + ot * 16 + l15) * 512 + c0 + ks * 32 + g * 8];
#pragma unroll
        for (int ks = 0; ks < 2; ++ks)
#pragma unroll
          for (int n2 = 0; n2 < 4; ++n2)
            oacc[ot][nth * 4 + n2] = MFMA16(af[ks], bb[n2][ks], oacc[ot][nth * 4 + n2]);
      }
    }
  }

  float gm = gamma[0];
#pragma unroll
  for (int ot = 0; ot < 4; ++ot)
#pragma unroll
    for (int nt = 0; nt < 8; ++nt)
#pragma unroll
      for (int r = 0; r < 4; ++r) {
        int o = w * 64 + ot * 16 + g * 4 + r;
        int n = qblk + nt * 16 + l15;
        size_t idx = ((size_t)(b * 512 + o)) * 4096 + n;
        out[idx] = gm * (oacc[ot][nt][r] + bo[o]) + x[idx];
      }
}

// ---------------------------------------------------------------------------
// Workspace map (38.9 MB):
//   V2 ws+0 (32MB, swizzled-tile V) | Qb ws+32M (2MB) | Kb ws+34M (2MB)
//   Wvb +36M (0.5MB) | Wob (0.5MB) | Wqkb (64KB)
//   d_out holds ONLY the final fp32 output (attn_f writes it directly).
// ---------------------------------------------------------------------------
extern "C" void kernel_launch(void* const* d_in, const int* in_sizes, int n_in,
                              void* d_out, int out_size, void* d_ws, size_t ws_size,
                              hipStream_t stream) {
  (void)in_sizes; (void)n_in; (void)out_size; (void)ws_size;
  const float* x     = (const float*)d_in[0];
  const float* Wq    = (const float*)d_in[1];
  const float* bq    = (const float*)d_in[2];
  const float* Wk    = (const float*)d_in[3];
  const float* bk    = (const float*)d_in[4];
  const float* Wv    = (const float*)d_in[5];
  const float* bv    = (const float*)d_in[6];
  const float* Wo    = (const float*)d_in[7];
  const float* bo    = (const float*)d_in[8];
  const float* gamma = (const float*)d_in[9];

  char* wsb = (char*)d_ws;
  u16* V2   = (u16*)(wsb + 0);
  u16* Qb   = (u16*)(wsb + (size_t)33554432);
  u16* Kb   = (u16*)(wsb + (size_t)35651584);
  u16* Wvb  = (u16*)(wsb + (size_t)37748736);
  u16* Wob  = (u16*)(wsb + (size_t)38273024);
  u16* Wqkb = (u16*)(wsb + (size_t)38797312);

  conv_w<<<256, 256, 0, stream>>>(Wv, Wvb, 65536);
  conv_w<<<256, 256, 0, stream>>>(Wo, Wob, 65536);
  conv_wqk<<<32, 256, 0, stream>>>(Wq, Wk, Wqkb);
  qkv_proj<<<dim3(64, 8, 2), 256, 0, stream>>>(x, Wvb, Wqkb, bv, bq, bk, V2, Qb, Kb);
  attn_f<<<256, 512, 0, stream>>>(Qb, Kb, V2, Wob, bo, gamma, x, (float*)d_out);
}